// Round 10
// baseline (124.326 us; speedup 1.0000x reference)
//
#include <hip/hip_runtime.h>
#include <hip/hip_bf16.h>
#include <cstdint>
#include <cstddef>

typedef __bf16 bf16_t;
typedef __bf16 bf16x8 __attribute__((ext_vector_type(8)));
typedef __bf16 bf16x4 __attribute__((ext_vector_type(4)));
typedef float f32x4 __attribute__((ext_vector_type(4)));
typedef float f32x16 __attribute__((ext_vector_type(16)));

constexpr int B_ = 4, T_ = 2048, C_ = 768, H_ = 12, D_ = 64;
constexpr size_t QKV_ELEMS = (size_t)B_ * H_ * T_ * D_;  // 6291456 per tensor

__device__ __forceinline__ void gload16(const bf16_t* g, bf16_t* l) {
    __builtin_amdgcn_global_load_lds(
        (const __attribute__((address_space(1))) unsigned int*)g,
        (__attribute__((address_space(3))) unsigned int*)l, 16, 0, 0);
}

// ---------------------------------------------------------------------------
// Streaming fp32 -> bf16 convert (two buffers in one launch).
// ---------------------------------------------------------------------------
__global__ __launch_bounds__(256)
void conv_bf16(const float* __restrict__ a, bf16_t* __restrict__ oa, int na8,
               const float* __restrict__ b, bf16_t* __restrict__ ob, int nb8)
{
    int i = blockIdx.x * 256 + threadIdx.x;
    if (i >= na8 + nb8) return;
    const float* src; bf16_t* dst; int idx;
    if (i < na8) { src = a; dst = oa; idx = i; }
    else         { src = b; dst = ob; idx = i - na8; }
    const float4* p = reinterpret_cast<const float4*>(src + (size_t)idx * 8);
    float4 f0 = p[0], f1 = p[1];
    bf16x8 t;
    t[0]=(bf16_t)f0.x; t[1]=(bf16_t)f0.y; t[2]=(bf16_t)f0.z; t[3]=(bf16_t)f0.w;
    t[4]=(bf16_t)f1.x; t[5]=(bf16_t)f1.y; t[6]=(bf16_t)f1.z; t[7]=(bf16_t)f1.w;
    *reinterpret_cast<bf16x8*>(dst + (size_t)idx * 8) = t;
}

// ---------------------------------------------------------------------------
// Kernel 1: QKV GEMM, m97 structure: bf16 inputs, global_load_lds(16B),
// linear LDS [128][64] with XOR-preswizzled source granules.
// ---------------------------------------------------------------------------
__global__ __launch_bounds__(256, 4)
void qkv_gemm(const bf16_t* __restrict__ xb, const bf16_t* __restrict__ wb,
              const float* __restrict__ bias,
              bf16_t* __restrict__ q, bf16_t* __restrict__ k, bf16_t* __restrict__ v)
{
    __shared__ alignas(16) bf16_t As[128 * 64];
    __shared__ alignas(16) bf16_t Bs[128 * 64];
    const int tid  = threadIdx.x;
    const int lane = tid & 63;
    const int w    = tid >> 6;
    const int wm = w >> 1, wn = w & 1;
    const int bm = blockIdx.x & 63;   // 64 m-blocks
    const int bn = blockIdx.x >> 6;   // 18 n-blocks
    const int m0 = bm * 128, n0 = bn * 128;
    const int lcol = lane & 15, lgrp = lane >> 4;
    const int srow = lane >> 3;             // 0..7 row within issue octet
    const int scol = ((lane & 7) ^ srow) * 8;  // pre-swizzled source granule

    const bf16_t* ag = xb + (size_t)(m0 + w * 32 + srow) * C_ + scol;
    const bf16_t* bg = wb + (size_t)(n0 + w * 32 + srow) * C_ + scol;
    bf16_t* al = &As[(w * 32) * 64];
    bf16_t* bl = &Bs[(w * 32) * 64];

    f32x4 acc[4][4] = {};

    for (int kt = 0; kt < C_; kt += 64) {
        __syncthreads();
        #pragma unroll
        for (int p = 0; p < 4; ++p) {
            gload16(ag + (size_t)(p * 8) * C_ + kt, al + p * 8 * 64);
            gload16(bg + (size_t)(p * 8) * C_ + kt, bl + p * 8 * 64);
        }
        __syncthreads();
        #pragma unroll
        for (int kk = 0; kk < 2; ++kk) {
            bf16x8 af[4], bfr[4];
            #pragma unroll
            for (int i = 0; i < 4; ++i) {
                const int R = wm * 64 + i * 16 + lcol;
                af[i] = *reinterpret_cast<const bf16x8*>(&As[R * 64 + (((kk*4 + lgrp) ^ (R & 7)) << 3)]);
            }
            #pragma unroll
            for (int j = 0; j < 4; ++j) {
                const int R = wn * 64 + j * 16 + lcol;
                bfr[j] = *reinterpret_cast<const bf16x8*>(&Bs[R * 64 + (((kk*4 + lgrp) ^ (R & 7)) << 3)]);
            }
            #pragma unroll
            for (int i = 0; i < 4; ++i)
                #pragma unroll
                for (int j = 0; j < 4; ++j)
                    acc[i][j] = __builtin_amdgcn_mfma_f32_16x16x32_bf16(af[i], bfr[j], acc[i][j], 0, 0, 0);
        }
    }

    #pragma unroll
    for (int j = 0; j < 4; ++j) {
        const int n = n0 + wn * 64 + j * 16 + lcol;
        const float bv = bias[n];
        const int s = n / C_, rem = n % C_;
        const int h = rem >> 6, d = rem & 63;
        bf16_t* dst = (s == 0) ? q : (s == 1) ? k : v;
        #pragma unroll
        for (int i = 0; i < 4; ++i) {
            #pragma unroll
            for (int r = 0; r < 4; ++r) {
                const int m = m0 + wm * 64 + i * 16 + lgrp * 4 + r;
                const int b = m >> 11, t = m & (T_ - 1);
                dst[(((size_t)(b * H_ + h)) * T_ + t) * D_ + d] = (bf16_t)(acc[i][j][r] + bv);
            }
        }
    }
}

// ---------------------------------------------------------------------------
// Kernel 2: causal flash attention, swapped-operand 32x32, 2-way SPLIT-K.
// Block = 64 q-rows, 4 waves: wave (wq, ws) = q-half wq, KV-parity ws.
// Per period p: stage tiles 2p and 2p+1 (parity LDS buffers), one compute
// tile per wave. 6144 waves total (2x parallelism, 1/2 serial depth).
// Deterministic per-lane merge of the two partial (m, l, O) at the end.
// (Exact R8-verified source — R9's fixed-bias trim bought only ~3us and
// failed post-timing revalidation; reverted per rigor.md.)
// ---------------------------------------------------------------------------
__global__ __launch_bounds__(256, 3)
void attn_fwd(const bf16_t* __restrict__ qg, const bf16_t* __restrict__ kg,
              const bf16_t* __restrict__ vg, bf16_t* __restrict__ og)
{
    __shared__ alignas(16) bf16_t lds[4 * 64 * 64];   // 32 KB
    bf16_t* Ks = lds;                  // [par][key][d], slot ^= key&7
    bf16_t* Vt = lds + 2 * 64 * 64;    // [par][d][key], slot ^= (d&7)^(d>>3)
    float*  scr = (float*)lds;         // merge scratch (overlays, post-loop)

    const int tid  = threadIdx.x;
    const int lane = tid & 63;
    const int w    = tid >> 6;               // 0..3
    const int wq   = w >> 1;                 // q-half
    const int ws   = w & 1;                  // KV parity
    const int l31  = lane & 31;
    const int hi   = lane >> 5;
    const int qi   = blockIdx.x / 48;        // 0..31
    const int bh   = blockIdx.x % 48;        // bh minor: same bh -> same XCD
    const int qt   = 31 - qi;                // heavy blocks first
    const int q0   = qt * 64;
    const int qw   = q0 + wq * 32;
    const size_t base = (size_t)bh * T_ * D_;
    const int qrow = qw + l31;

    const float SCL = 0.125f * 1.44269504f;  // scale * log2(e)
    bf16x8 bq[4];
    #pragma unroll
    for (int kt = 0; kt < 4; ++kt) {
        bf16x8 t = *reinterpret_cast<const bf16x8*>(qg + base + (size_t)qrow * D_ + kt*16 + hi*8);
        #pragma unroll
        for (int e = 0; e < 8; ++e) t[e] = (bf16_t)((float)t[e] * SCL);
        bq[kt] = t;
    }

    f32x16 ot0 = {};
    f32x16 ot1 = {};
    float m = -1e30f, rowl = 0.0f;

    const int sgr = tid & 7;
    union U8 { bf16x8 v; uint32_t u[4]; };
    union UP { uint32_t u[4]; bf16x8 v; };

    const int ntiles = qt + 1;
    const int np = (ntiles + 1) >> 1;

    for (int p = 0; p < np; ++p) {
        __syncthreads();               // prior compute done -> LDS writable
        #pragma unroll
        for (int par = 0; par < 2; ++par) {
            const int t = 2 * p + par;
            if (t >= ntiles) break;    // block-uniform
            const size_t toff = (size_t)t * 64 * D_;
            // K: 512 granules by 256 threads, 2 passes
            #pragma unroll
            for (int pp = 0; pp < 2; ++pp) {
                const int g = pp * 256 + tid;
                const int key = g >> 3, slot = g & 7;
                bf16x8 kv = *reinterpret_cast<const bf16x8*>(
                    kg + base + toff + (size_t)key * D_ + slot * 8);
                *reinterpret_cast<bf16x8*>(
                    Ks + par * 4096 + key * 64 + ((slot ^ (key & 7)) << 3)) = kv;
            }
            // V transposed, pair-packed b32 writes
            {
                const int va = tid >> 3;   // key pair (2va, 2va+1)
                U8 v0, v1;
                v0.v = *reinterpret_cast<const bf16x8*>(
                    vg + base + toff + (size_t)(2 * va) * D_ + sgr * 8);
                v1.v = *reinterpret_cast<const bf16x8*>(
                    vg + base + toff + (size_t)(2 * va + 1) * D_ + sgr * 8);
                #pragma unroll
                for (int j = 0; j < 8; ++j) {
                    const int d = sgr * 8 + j;
                    const int ss = ((va >> 2) ^ j ^ sgr) & 7;
                    uint32_t wd = __builtin_amdgcn_perm(v1.u[j >> 1], v0.u[j >> 1],
                                                        (j & 1) ? 0x07060302u : 0x05040100u);
                    *reinterpret_cast<uint32_t*>(
                        Vt + par * 4096 + d * 64 + ss * 8 + (va & 3) * 2) = wd;
                }
            }
        }
        __syncthreads();               // LDS ready

        const int t = 2 * p + ws;      // my tile (wave-uniform)
        if (t >= ntiles) continue;
        const bf16_t* Kb = Ks + ws * 4096;
        const bf16_t* Vb = Vt + ws * 4096;
        const int kv0 = t * 64;

        #pragma unroll
        for (int sk = 0; sk < 2; ++sk) {
            const int kvs = kv0 + sk * 32;
            if (sk == 1 && kvs > qw + 31) continue;   // wave-uniform skip

            // S^T = K . Q  (32 keys x 32 q), accumulate over D=64
            f32x16 s = {};
            __builtin_amdgcn_s_setprio(1);
            #pragma unroll
            for (int kt = 0; kt < 4; ++kt) {
                const int keyl = sk * 32 + l31;
                const int slot = kt * 2 + hi;
                bf16x8 ka = *reinterpret_cast<const bf16x8*>(
                    Kb + keyl * 64 + ((slot ^ (keyl & 7)) << 3));
                s = __builtin_amdgcn_mfma_f32_32x32x16_bf16(ka, bq[kt], s, 0, 0, 0);
            }
            __builtin_amdgcn_s_setprio(0);
            // causal mask (boundary subtile only)
            if (kvs + 31 > qw) {
                #pragma unroll
                for (int r = 0; r < 16; ++r) {
                    const int key = kvs + (r & 3) + 8 * (r >> 2) + 4 * hi;
                    if (key > qrow) s[r] = -1e30f;
                }
            }
            // lane-local online softmax (log2 domain); max via max3 tree
            float a0 = fmaxf(fmaxf(s[0],  s[1]),  s[2]);
            float a1 = fmaxf(fmaxf(s[3],  s[4]),  s[5]);
            float a2 = fmaxf(fmaxf(s[6],  s[7]),  s[8]);
            float a3 = fmaxf(fmaxf(s[9],  s[10]), s[11]);
            float a4 = fmaxf(fmaxf(s[12], s[13]), s[14]);
            float b0 = fmaxf(fmaxf(a0, a1), a2);
            float b1 = fmaxf(fmaxf(a3, a4), s[15]);
            float mt = fmaxf(b0, b1);
            mt = fmaxf(mt, __shfl_xor(mt, 32));
            if (!__all(mt <= m + 8.0f)) {   // defer-max (T13)
                const float mnew = fmaxf(m, mt);
                const float alpha = exp2f(m - mnew);
                #pragma unroll
                for (int r = 0; r < 16; ++r) { ot0[r] *= alpha; ot1[r] *= alpha; }
                rowl *= alpha;
                m = mnew;
            }
            #pragma unroll
            for (int r = 0; r < 16; ++r) s[r] = exp2f(s[r] - m);
            float t0 = (s[0]+s[1]) + (s[2]+s[3]);
            float t1 = (s[4]+s[5]) + (s[6]+s[7]);
            float t2 = (s[8]+s[9]) + (s[10]+s[11]);
            float t3 = (s[12]+s[13]) + (s[14]+s[15]);
            float rs = (t0 + t1) + (t2 + t3);
            rs += __shfl_xor(rs, 32);
            rowl += rs;

            // pack P -> bf16 B-fragments via cvt_pk + permlane32_swap (T12)
            uint32_t c0, c1, c2, c3, c4, c5, c6, c7;
            asm("v_cvt_pk_bf16_f32 %0, %1, %2" : "=v"(c0) : "v"(s[0]),  "v"(s[1]));
            asm("v_cvt_pk_bf16_f32 %0, %1, %2" : "=v"(c1) : "v"(s[2]),  "v"(s[3]));
            asm("v_cvt_pk_bf16_f32 %0, %1, %2" : "=v"(c2) : "v"(s[4]),  "v"(s[5]));
            asm("v_cvt_pk_bf16_f32 %0, %1, %2" : "=v"(c3) : "v"(s[6]),  "v"(s[7]));
            asm("v_cvt_pk_bf16_f32 %0, %1, %2" : "=v"(c4) : "v"(s[8]),  "v"(s[9]));
            asm("v_cvt_pk_bf16_f32 %0, %1, %2" : "=v"(c5) : "v"(s[10]), "v"(s[11]));
            asm("v_cvt_pk_bf16_f32 %0, %1, %2" : "=v"(c6) : "v"(s[12]), "v"(s[13]));
            asm("v_cvt_pk_bf16_f32 %0, %1, %2" : "=v"(c7) : "v"(s[14]), "v"(s[15]));
            asm("v_permlane32_swap_b32 %0, %1" : "+v"(c0), "+v"(c2));
            asm("v_permlane32_swap_b32 %0, %1" : "+v"(c1), "+v"(c3));
            asm("v_permlane32_swap_b32 %0, %1" : "+v"(c4), "+v"(c6));
            asm("v_permlane32_swap_b32 %0, %1" : "+v"(c5), "+v"(c7));
            UP pa0; pa0.u[0] = c0; pa0.u[1] = c1; pa0.u[2] = c2; pa0.u[3] = c3;
            UP pa1; pa1.u[0] = c4; pa1.u[1] = c5; pa1.u[2] = c6; pa1.u[3] = c7;

            // O^T += V^T . P^T
            __builtin_amdgcn_s_setprio(1);
            #pragma unroll
            for (int dblk = 0; dblk < 2; ++dblk) {
                const int d = dblk * 32 + l31;
                f32x16& o = dblk ? ot1 : ot0;
                #pragma unroll
                for (int ktile = 0; ktile < 2; ++ktile) {
                    const int kslot = sk * 4 + ktile * 2 + hi;
                    const int ss = kslot ^ (d & 7) ^ ((d >> 3) & 7);
                    bf16x8 va = *reinterpret_cast<const bf16x8*>(Vb + d * 64 + (ss << 3));
                    o = __builtin_amdgcn_mfma_f32_32x32x16_bf16(va, ktile ? pa1.v : pa0.v, o, 0, 0, 0);
                }
            }
            __builtin_amdgcn_s_setprio(0);
        }
    }

    // ---- split-K merge: ws=1 publishes (O, m, l); ws=0 combines & writes ----
    __syncthreads();                       // all waves done with K/V LDS
    if (ws == 1) {
        float* s = scr + (wq * 64 + lane) * 35;   // stride 35: conflict-free
        #pragma unroll
        for (int r = 0; r < 16; ++r) { s[r] = ot0[r]; s[16 + r] = ot1[r]; }
        s[32] = m; s[33] = rowl;
    }
    __syncthreads();
    if (ws == 0) {
        const float* s = scr + (wq * 64 + lane) * 35;
        const float m1 = s[32], l1 = s[33];
        const float mn = fmaxf(m, m1);
        const float f0 = exp2f(m - mn);
        const float f1 = exp2f(m1 - mn);       // 0 if partner empty (m1=-1e30)
        const float linv = 1.0f / (rowl * f0 + l1 * f1);
        const int b = bh / H_, h = bh % H_;
        bf16_t* dst = &og[((size_t)b * T_ + qrow) * C_ + h * D_];
        #pragma unroll
        for (int dblk = 0; dblk < 2; ++dblk) {
            const f32x16& o = dblk ? ot1 : ot0;
            #pragma unroll
            for (int qd = 0; qd < 4; ++qd) {
                bf16x4 v4;
                #pragma unroll
                for (int r = 0; r < 4; ++r) {
                    const float ov = o[qd * 4 + r] * f0 + s[dblk * 16 + qd * 4 + r] * f1;
                    v4[r] = (bf16_t)(ov * linv);
                }
                *reinterpret_cast<bf16x4*>(dst + dblk * 32 + qd * 8 + hi * 4) = v4;
            }
        }
    }
}

// ---------------------------------------------------------------------------
// Kernel 3: output projection, m97 structure. out fp32 = ao * wpb^T + bias.
// ---------------------------------------------------------------------------
__global__ __launch_bounds__(256, 4)
void proj_gemm(const bf16_t* __restrict__ ao, const bf16_t* __restrict__ wpb,
               const float* __restrict__ bias, float* __restrict__ out)
{
    __shared__ alignas(16) bf16_t As[128 * 64];
    __shared__ alignas(16) bf16_t Bs[128 * 64];
    const int tid  = threadIdx.x;
    const int lane = tid & 63;
    const int w    = tid >> 6;
    const int wm = w >> 1, wn = w & 1;
    const int bm = blockIdx.x & 63;   // 64 m-blocks
    const int bn = blockIdx.x >> 6;   // 6 n-blocks
    const int m0 = bm * 128, n0 = bn * 128;
    const int lcol = lane & 15, lgrp = lane >> 4;
    const int srow = lane >> 3;
    const int scol = ((lane & 7) ^ srow) * 8;

    const bf16_t* ag = ao  + (size_t)(m0 + w * 32 + srow) * C_ + scol;
    const bf16_t* bg = wpb + (size_t)(n0 + w * 32 + srow) * C_ + scol;
    bf16_t* al = &As[(w * 32) * 64];
    bf16_t* bl = &Bs[(w * 32) * 64];

    f32x4 acc[4][4] = {};

    for (int kt = 0; kt < C_; kt += 64) {
        __syncthreads();
        #pragma unroll
        for (int p = 0; p < 4; ++p) {
            gload16(ag + (size_t)(p * 8) * C_ + kt, al + p * 8 * 64);
            gload16(bg + (size_t)(p * 8) * C_ + kt, bl + p * 8 * 64);
        }
        __syncthreads();
        #pragma unroll
        for (int kk = 0; kk < 2; ++kk) {
            bf16x8 af[4], bfr[4];
            #pragma unroll
            for (int i = 0; i < 4; ++i) {
                const int R = wm * 64 + i * 16 + lcol;
                af[i] = *reinterpret_cast<const bf16x8*>(&As[R * 64 + (((kk*4 + lgrp) ^ (R & 7)) << 3)]);
            }
            #pragma unroll
            for (int j = 0; j < 4; ++j) {
                const int R = wn * 64 + j * 16 + lcol;
                bfr[j] = *reinterpret_cast<const bf16x8*>(&Bs[R * 64 + (((kk*4 + lgrp) ^ (R & 7)) << 3)]);
            }
            #pragma unroll
            for (int i = 0; i < 4; ++i)
                #pragma unroll
                for (int j = 0; j < 4; ++j)
                    acc[i][j] = __builtin_amdgcn_mfma_f32_16x16x32_bf16(af[i], bfr[j], acc[i][j], 0, 0, 0);
        }
    }

    #pragma unroll
    for (int j = 0; j < 4; ++j) {
        const int n = n0 + wn * 64 + j * 16 + lcol;
        const float bv = bias[n];
        #pragma unroll
        for (int i = 0; i < 4; ++i) {
            #pragma unroll
            for (int r = 0; r < 4; ++r) {
                const int m = m0 + wm * 64 + i * 16 + lgrp * 4 + r;
                out[(size_t)m * C_ + n] = acc[i][j][r] + bv;
            }
        }
    }
}

// ---------------------------------------------------------------------------
extern "C" void kernel_launch(void* const* d_in, const int* in_sizes, int n_in,
                              void* d_out, int out_size, void* d_ws, size_t ws_size,
                              hipStream_t stream)
{
    const float* x      = (const float*)d_in[0];
    const float* w_qkv  = (const float*)d_in[1];
    const float* b_qkv  = (const float*)d_in[2];
    const float* w_proj = (const float*)d_in[3];
    const float* b_proj = (const float*)d_in[4];
    float* out = (float*)d_out;

    bf16_t* ws = (bf16_t*)d_ws;
    bf16_t* q   = ws;
    bf16_t* k   = ws +     QKV_ELEMS;
    bf16_t* v   = ws + 2 * QKV_ELEMS;
    bf16_t* ao  = ws + 3 * QKV_ELEMS;
    bf16_t* xb  = ao;               // alias: dead once qkv_gemm completes
    bf16_t* wqb = (bf16_t*)d_out;   // alias: out written only by proj at the end
    bf16_t* wpb = k;                // alias: k dead after attn; converted just-in-time

    conv_bf16<<<dim3(3936), 256, 0, stream>>>(x, xb, 786432, w_qkv, wqb, 221184);
    qkv_gemm<<<dim3(64 * 18), 256, 0, stream>>>(xb, wqb, b_qkv, q, k, v);
    attn_fwd<<<dim3(32 * 48), 256, 0, stream>>>(q, k, v, ao);
    conv_bf16<<<dim3(288), 256, 0, stream>>>(w_proj, wpb, 73728, w_proj, wpb, 0);
    proj_gemm<<<dim3(64 * 6), 256, 0, stream>>>(ao, wpb, b_proj, out);
}

// Round 11
// 119.012 us; speedup vs baseline: 1.0447x; 1.0447x over previous
//
#include <hip/hip_runtime.h>
#include <hip/hip_bf16.h>
#include <cstdint>
#include <cstddef>

typedef __bf16 bf16_t;
typedef __bf16 bf16x8 __attribute__((ext_vector_type(8)));
typedef __bf16 bf16x4 __attribute__((ext_vector_type(4)));
typedef float f32x4 __attribute__((ext_vector_type(4)));
typedef float f32x16 __attribute__((ext_vector_type(16)));

constexpr int B_ = 4, T_ = 2048, C_ = 768, H_ = 12, D_ = 64;
constexpr size_t QKV_ELEMS = (size_t)B_ * H_ * T_ * D_;   // 6291456 per tensor
constexpr size_t AO_ELEMS  = (size_t)B_ * T_ * C_;        // 12582912
constexpr size_t WPB_ELEMS = (size_t)C_ * C_;             // 589824

__device__ __forceinline__ void gload16(const bf16_t* g, bf16_t* l) {
    __builtin_amdgcn_global_load_lds(
        (const __attribute__((address_space(1))) unsigned int*)g,
        (__attribute__((address_space(3))) unsigned int*)l, 16, 0, 0);
}

// ---------------------------------------------------------------------------
// Streaming fp32 -> bf16 convert (up to three buffers in one launch).
// ---------------------------------------------------------------------------
__global__ __launch_bounds__(256)
void conv_bf16_3(const float* __restrict__ a, bf16_t* __restrict__ oa, int na8,
                 const float* __restrict__ b, bf16_t* __restrict__ ob, int nb8,
                 const float* __restrict__ c, bf16_t* __restrict__ oc, int nc8)
{
    int i = blockIdx.x * 256 + threadIdx.x;
    if (i >= na8 + nb8 + nc8) return;
    const float* src; bf16_t* dst; int idx;
    if (i < na8)             { src = a; dst = oa; idx = i; }
    else if (i < na8 + nb8)  { src = b; dst = ob; idx = i - na8; }
    else                     { src = c; dst = oc; idx = i - na8 - nb8; }
    const float4* p = reinterpret_cast<const float4*>(src + (size_t)idx * 8);
    float4 f0 = p[0], f1 = p[1];
    bf16x8 t;
    t[0]=(bf16_t)f0.x; t[1]=(bf16_t)f0.y; t[2]=(bf16_t)f0.z; t[3]=(bf16_t)f0.w;
    t[4]=(bf16_t)f1.x; t[5]=(bf16_t)f1.y; t[6]=(bf16_t)f1.z; t[7]=(bf16_t)f1.w;
    *reinterpret_cast<bf16x8*>(dst + (size_t)idx * 8) = t;
}

// ---------------------------------------------------------------------------
// Kernel 1: QKV GEMM, m97 structure: bf16 inputs, global_load_lds(16B),
// linear LDS [128][64] with XOR-preswizzled source granules.
// ---------------------------------------------------------------------------
__global__ __launch_bounds__(256, 3)
void qkv_gemm(const bf16_t* __restrict__ xb, const bf16_t* __restrict__ wb,
              const float* __restrict__ bias,
              bf16_t* __restrict__ q, bf16_t* __restrict__ k, bf16_t* __restrict__ v)
{
    __shared__ alignas(16) bf16_t As[128 * 64];
    __shared__ alignas(16) bf16_t Bs[128 * 64];
    const int tid  = threadIdx.x;
    const int lane = tid & 63;
    const int w    = tid >> 6;
    const int wm = w >> 1, wn = w & 1;
    const int bm = blockIdx.x & 63;   // 64 m-blocks
    const int bn = blockIdx.x >> 6;   // 18 n-blocks
    const int m0 = bm * 128, n0 = bn * 128;
    const int lcol = lane & 15, lgrp = lane >> 4;
    const int srow = lane >> 3;             // 0..7 row within issue octet
    const int scol = ((lane & 7) ^ srow) * 8;  // pre-swizzled source granule

    const bf16_t* ag = xb + (size_t)(m0 + w * 32 + srow) * C_ + scol;
    const bf16_t* bg = wb + (size_t)(n0 + w * 32 + srow) * C_ + scol;
    bf16_t* al = &As[(w * 32) * 64];
    bf16_t* bl = &Bs[(w * 32) * 64];

    f32x4 acc[4][4] = {};

    for (int kt = 0; kt < C_; kt += 64) {
        __syncthreads();
        #pragma unroll
        for (int p = 0; p < 4; ++p) {
            gload16(ag + (size_t)(p * 8) * C_ + kt, al + p * 8 * 64);
            gload16(bg + (size_t)(p * 8) * C_ + kt, bl + p * 8 * 64);
        }
        __syncthreads();
        #pragma unroll
        for (int kk = 0; kk < 2; ++kk) {
            bf16x8 af[4], bfr[4];
            #pragma unroll
            for (int i = 0; i < 4; ++i) {
                const int R = wm * 64 + i * 16 + lcol;
                af[i] = *reinterpret_cast<const bf16x8*>(&As[R * 64 + (((kk*4 + lgrp) ^ (R & 7)) << 3)]);
            }
            #pragma unroll
            for (int j = 0; j < 4; ++j) {
                const int R = wn * 64 + j * 16 + lcol;
                bfr[j] = *reinterpret_cast<const bf16x8*>(&Bs[R * 64 + (((kk*4 + lgrp) ^ (R & 7)) << 3)]);
            }
            #pragma unroll
            for (int i = 0; i < 4; ++i)
                #pragma unroll
                for (int j = 0; j < 4; ++j)
                    acc[i][j] = __builtin_amdgcn_mfma_f32_16x16x32_bf16(af[i], bfr[j], acc[i][j], 0, 0, 0);
        }
    }

    #pragma unroll
    for (int j = 0; j < 4; ++j) {
        const int n = n0 + wn * 64 + j * 16 + lcol;
        const float bv = bias[n];
        const int s = n / C_, rem = n % C_;
        const int h = rem >> 6, d = rem & 63;
        bf16_t* dst = (s == 0) ? q : (s == 1) ? k : v;
        #pragma unroll
        for (int i = 0; i < 4; ++i) {
            #pragma unroll
            for (int r = 0; r < 4; ++r) {
                const int m = m0 + wm * 64 + i * 16 + lgrp * 4 + r;
                const int b = m >> 11, t = m & (T_ - 1);
                dst[(((size_t)(b * H_ + h)) * T_ + t) * D_ + d] = (bf16_t)(acc[i][j][r] + bv);
            }
        }
    }
}

// ---------------------------------------------------------------------------
// Kernel 2: causal flash attention, swapped-operand 32x32, 2-way SPLIT-K.
// Exact R8-verified source (best measured config: attn 63.5us, occ 33%).
// ---------------------------------------------------------------------------
__global__ __launch_bounds__(256, 3)
void attn_fwd(const bf16_t* __restrict__ qg, const bf16_t* __restrict__ kg,
              const bf16_t* __restrict__ vg, bf16_t* __restrict__ og)
{
    __shared__ alignas(16) bf16_t lds[4 * 64 * 64];   // 32 KB
    bf16_t* Ks = lds;                  // [par][key][d], slot ^= key&7
    bf16_t* Vt = lds + 2 * 64 * 64;    // [par][d][key], slot ^= (d&7)^(d>>3)
    float*  scr = (float*)lds;         // merge scratch (overlays, post-loop)

    const int tid  = threadIdx.x;
    const int lane = tid & 63;
    const int w    = tid >> 6;               // 0..3
    const int wq   = w >> 1;                 // q-half
    const int ws   = w & 1;                  // KV parity
    const int l31  = lane & 31;
    const int hi   = lane >> 5;
    const int qi   = blockIdx.x / 48;        // 0..31
    const int bh   = blockIdx.x % 48;        // bh minor: same bh -> same XCD
    const int qt   = 31 - qi;                // heavy blocks first
    const int q0   = qt * 64;
    const int qw   = q0 + wq * 32;
    const size_t base = (size_t)bh * T_ * D_;
    const int qrow = qw + l31;

    const float SCL = 0.125f * 1.44269504f;  // scale * log2(e)
    bf16x8 bq[4];
    #pragma unroll
    for (int kt = 0; kt < 4; ++kt) {
        bf16x8 t = *reinterpret_cast<const bf16x8*>(qg + base + (size_t)qrow * D_ + kt*16 + hi*8);
        #pragma unroll
        for (int e = 0; e < 8; ++e) t[e] = (bf16_t)((float)t[e] * SCL);
        bq[kt] = t;
    }

    f32x16 ot0 = {};
    f32x16 ot1 = {};
    float m = -1e30f, rowl = 0.0f;

    const int sgr = tid & 7;
    union U8 { bf16x8 v; uint32_t u[4]; };
    union UP { uint32_t u[4]; bf16x8 v; };

    const int ntiles = qt + 1;
    const int np = (ntiles + 1) >> 1;

    for (int p = 0; p < np; ++p) {
        __syncthreads();               // prior compute done -> LDS writable
        #pragma unroll
        for (int par = 0; par < 2; ++par) {
            const int t = 2 * p + par;
            if (t >= ntiles) break;    // block-uniform
            const size_t toff = (size_t)t * 64 * D_;
            // K: 512 granules by 256 threads, 2 passes
            #pragma unroll
            for (int pp = 0; pp < 2; ++pp) {
                const int g = pp * 256 + tid;
                const int key = g >> 3, slot = g & 7;
                bf16x8 kv = *reinterpret_cast<const bf16x8*>(
                    kg + base + toff + (size_t)key * D_ + slot * 8);
                *reinterpret_cast<bf16x8*>(
                    Ks + par * 4096 + key * 64 + ((slot ^ (key & 7)) << 3)) = kv;
            }
            // V transposed, pair-packed b32 writes
            {
                const int va = tid >> 3;   // key pair (2va, 2va+1)
                U8 v0, v1;
                v0.v = *reinterpret_cast<const bf16x8*>(
                    vg + base + toff + (size_t)(2 * va) * D_ + sgr * 8);
                v1.v = *reinterpret_cast<const bf16x8*>(
                    vg + base + toff + (size_t)(2 * va + 1) * D_ + sgr * 8);
                #pragma unroll
                for (int j = 0; j < 8; ++j) {
                    const int d = sgr * 8 + j;
                    const int ss = ((va >> 2) ^ j ^ sgr) & 7;
                    uint32_t wd = __builtin_amdgcn_perm(v1.u[j >> 1], v0.u[j >> 1],
                                                        (j & 1) ? 0x07060302u : 0x05040100u);
                    *reinterpret_cast<uint32_t*>(
                        Vt + par * 4096 + d * 64 + ss * 8 + (va & 3) * 2) = wd;
                }
            }
        }
        __syncthreads();               // LDS ready

        const int t = 2 * p + ws;      // my tile (wave-uniform)
        if (t >= ntiles) continue;
        const bf16_t* Kb = Ks + ws * 4096;
        const bf16_t* Vb = Vt + ws * 4096;
        const int kv0 = t * 64;

        #pragma unroll
        for (int sk = 0; sk < 2; ++sk) {
            const int kvs = kv0 + sk * 32;
            if (sk == 1 && kvs > qw + 31) continue;   // wave-uniform skip

            // S^T = K . Q  (32 keys x 32 q), accumulate over D=64
            f32x16 s = {};
            __builtin_amdgcn_s_setprio(1);
            #pragma unroll
            for (int kt = 0; kt < 4; ++kt) {
                const int keyl = sk * 32 + l31;
                const int slot = kt * 2 + hi;
                bf16x8 ka = *reinterpret_cast<const bf16x8*>(
                    Kb + keyl * 64 + ((slot ^ (keyl & 7)) << 3));
                s = __builtin_amdgcn_mfma_f32_32x32x16_bf16(ka, bq[kt], s, 0, 0, 0);
            }
            __builtin_amdgcn_s_setprio(0);
            // causal mask (boundary subtile only)
            if (kvs + 31 > qw) {
                #pragma unroll
                for (int r = 0; r < 16; ++r) {
                    const int key = kvs + (r & 3) + 8 * (r >> 2) + 4 * hi;
                    if (key > qrow) s[r] = -1e30f;
                }
            }
            // lane-local online softmax (log2 domain); max via max3 tree
            float a0 = fmaxf(fmaxf(s[0],  s[1]),  s[2]);
            float a1 = fmaxf(fmaxf(s[3],  s[4]),  s[5]);
            float a2 = fmaxf(fmaxf(s[6],  s[7]),  s[8]);
            float a3 = fmaxf(fmaxf(s[9],  s[10]), s[11]);
            float a4 = fmaxf(fmaxf(s[12], s[13]), s[14]);
            float b0 = fmaxf(fmaxf(a0, a1), a2);
            float b1 = fmaxf(fmaxf(a3, a4), s[15]);
            float mt = fmaxf(b0, b1);
            mt = fmaxf(mt, __shfl_xor(mt, 32));
            if (!__all(mt <= m + 8.0f)) {   // defer-max (T13)
                const float mnew = fmaxf(m, mt);
                const float alpha = exp2f(m - mnew);
                #pragma unroll
                for (int r = 0; r < 16; ++r) { ot0[r] *= alpha; ot1[r] *= alpha; }
                rowl *= alpha;
                m = mnew;
            }
            #pragma unroll
            for (int r = 0; r < 16; ++r) s[r] = exp2f(s[r] - m);
            float t0 = (s[0]+s[1]) + (s[2]+s[3]);
            float t1 = (s[4]+s[5]) + (s[6]+s[7]);
            float t2 = (s[8]+s[9]) + (s[10]+s[11]);
            float t3 = (s[12]+s[13]) + (s[14]+s[15]);
            float rs = (t0 + t1) + (t2 + t3);
            rs += __shfl_xor(rs, 32);
            rowl += rs;

            // pack P -> bf16 B-fragments via cvt_pk + permlane32_swap (T12)
            uint32_t c0, c1, c2, c3, c4, c5, c6, c7;
            asm("v_cvt_pk_bf16_f32 %0, %1, %2" : "=v"(c0) : "v"(s[0]),  "v"(s[1]));
            asm("v_cvt_pk_bf16_f32 %0, %1, %2" : "=v"(c1) : "v"(s[2]),  "v"(s[3]));
            asm("v_cvt_pk_bf16_f32 %0, %1, %2" : "=v"(c2) : "v"(s[4]),  "v"(s[5]));
            asm("v_cvt_pk_bf16_f32 %0, %1, %2" : "=v"(c3) : "v"(s[6]),  "v"(s[7]));
            asm("v_cvt_pk_bf16_f32 %0, %1, %2" : "=v"(c4) : "v"(s[8]),  "v"(s[9]));
            asm("v_cvt_pk_bf16_f32 %0, %1, %2" : "=v"(c5) : "v"(s[10]), "v"(s[11]));
            asm("v_cvt_pk_bf16_f32 %0, %1, %2" : "=v"(c6) : "v"(s[12]), "v"(s[13]));
            asm("v_cvt_pk_bf16_f32 %0, %1, %2" : "=v"(c7) : "v"(s[14]), "v"(s[15]));
            asm("v_permlane32_swap_b32 %0, %1" : "+v"(c0), "+v"(c2));
            asm("v_permlane32_swap_b32 %0, %1" : "+v"(c1), "+v"(c3));
            asm("v_permlane32_swap_b32 %0, %1" : "+v"(c4), "+v"(c6));
            asm("v_permlane32_swap_b32 %0, %1" : "+v"(c5), "+v"(c7));
            UP pa0; pa0.u[0] = c0; pa0.u[1] = c1; pa0.u[2] = c2; pa0.u[3] = c3;
            UP pa1; pa1.u[0] = c4; pa1.u[1] = c5; pa1.u[2] = c6; pa1.u[3] = c7;

            // O^T += V^T . P^T
            __builtin_amdgcn_s_setprio(1);
            #pragma unroll
            for (int dblk = 0; dblk < 2; ++dblk) {
                const int d = dblk * 32 + l31;
                f32x16& o = dblk ? ot1 : ot0;
                #pragma unroll
                for (int ktile = 0; ktile < 2; ++ktile) {
                    const int kslot = sk * 4 + ktile * 2 + hi;
                    const int ss = kslot ^ (d & 7) ^ ((d >> 3) & 7);
                    bf16x8 va = *reinterpret_cast<const bf16x8*>(Vb + d * 64 + (ss << 3));
                    o = __builtin_amdgcn_mfma_f32_32x32x16_bf16(va, ktile ? pa1.v : pa0.v, o, 0, 0, 0);
                }
            }
            __builtin_amdgcn_s_setprio(0);
        }
    }

    // ---- split-K merge: ws=1 publishes (O, m, l); ws=0 combines & writes ----
    __syncthreads();                       // all waves done with K/V LDS
    if (ws == 1) {
        float* s = scr + (wq * 64 + lane) * 35;   // stride 35: conflict-free
        #pragma unroll
        for (int r = 0; r < 16; ++r) { s[r] = ot0[r]; s[16 + r] = ot1[r]; }
        s[32] = m; s[33] = rowl;
    }
    __syncthreads();
    if (ws == 0) {
        const float* s = scr + (wq * 64 + lane) * 35;
        const float m1 = s[32], l1 = s[33];
        const float mn = fmaxf(m, m1);
        const float f0 = exp2f(m - mn);
        const float f1 = exp2f(m1 - mn);       // 0 if partner empty (m1=-1e30)
        const float linv = 1.0f / (rowl * f0 + l1 * f1);
        const int b = bh / H_, h = bh % H_;
        bf16_t* dst = &og[((size_t)b * T_ + qrow) * C_ + h * D_];
        #pragma unroll
        for (int dblk = 0; dblk < 2; ++dblk) {
            const f32x16& o = dblk ? ot1 : ot0;
            #pragma unroll
            for (int qd = 0; qd < 4; ++qd) {
                bf16x4 v4;
                #pragma unroll
                for (int r = 0; r < 4; ++r) {
                    const float ov = o[qd * 4 + r] * f0 + s[dblk * 16 + qd * 4 + r] * f1;
                    v4[r] = (bf16_t)(ov * linv);
                }
                *reinterpret_cast<bf16x4*>(dst + dblk * 32 + qd * 8 + hi * 4) = v4;
            }
        }
    }
}

// ---------------------------------------------------------------------------
// Kernel 3: output projection, m97 structure. out fp32 = ao * wpb^T + bias.
// ---------------------------------------------------------------------------
__global__ __launch_bounds__(256, 3)
void proj_gemm(const bf16_t* __restrict__ ao, const bf16_t* __restrict__ wpb,
               const float* __restrict__ bias, float* __restrict__ out)
{
    __shared__ alignas(16) bf16_t As[128 * 64];
    __shared__ alignas(16) bf16_t Bs[128 * 64];
    const int tid  = threadIdx.x;
    const int lane = tid & 63;
    const int w    = tid >> 6;
    const int wm = w >> 1, wn = w & 1;
    const int bm = blockIdx.x & 63;   // 64 m-blocks
    const int bn = blockIdx.x >> 6;   // 6 n-blocks
    const int m0 = bm * 128, n0 = bn * 128;
    const int lcol = lane & 15, lgrp = lane >> 4;
    const int srow = lane >> 3;
    const int scol = ((lane & 7) ^ srow) * 8;

    const bf16_t* ag = ao  + (size_t)(m0 + w * 32 + srow) * C_ + scol;
    const bf16_t* bg = wpb + (size_t)(n0 + w * 32 + srow) * C_ + scol;
    bf16_t* al = &As[(w * 32) * 64];
    bf16_t* bl = &Bs[(w * 32) * 64];

    f32x4 acc[4][4] = {};

    for (int kt = 0; kt < C_; kt += 64) {
        __syncthreads();
        #pragma unroll
        for (int p = 0; p < 4; ++p) {
            gload16(ag + (size_t)(p * 8) * C_ + kt, al + p * 8 * 64);
            gload16(bg + (size_t)(p * 8) * C_ + kt, bl + p * 8 * 64);
        }
        __syncthreads();
        #pragma unroll
        for (int kk = 0; kk < 2; ++kk) {
            bf16x8 af[4], bfr[4];
            #pragma unroll
            for (int i = 0; i < 4; ++i) {
                const int R = wm * 64 + i * 16 + lcol;
                af[i] = *reinterpret_cast<const bf16x8*>(&As[R * 64 + (((kk*4 + lgrp) ^ (R & 7)) << 3)]);
            }
            #pragma unroll
            for (int j = 0; j < 4; ++j) {
                const int R = wn * 64 + j * 16 + lcol;
                bfr[j] = *reinterpret_cast<const bf16x8*>(&Bs[R * 64 + (((kk*4 + lgrp) ^ (R & 7)) << 3)]);
            }
            #pragma unroll
            for (int i = 0; i < 4; ++i)
                #pragma unroll
                for (int j = 0; j < 4; ++j)
                    acc[i][j] = __builtin_amdgcn_mfma_f32_16x16x32_bf16(af[i], bfr[j], acc[i][j], 0, 0, 0);
        }
    }

    #pragma unroll
    for (int j = 0; j < 4; ++j) {
        const int n = n0 + wn * 64 + j * 16 + lcol;
        const float bv = bias[n];
        #pragma unroll
        for (int i = 0; i < 4; ++i) {
            #pragma unroll
            for (int r = 0; r < 4; ++r) {
                const int m = m0 + wm * 64 + i * 16 + lgrp * 4 + r;
                out[(size_t)m * C_ + n] = acc[i][j][r] + bv;
            }
        }
    }
}

// ---------------------------------------------------------------------------
extern "C" void kernel_launch(void* const* d_in, const int* in_sizes, int n_in,
                              void* d_out, int out_size, void* d_ws, size_t ws_size,
                              hipStream_t stream)
{
    const float* x      = (const float*)d_in[0];
    const float* w_qkv  = (const float*)d_in[1];
    const float* b_qkv  = (const float*)d_in[2];
    const float* w_proj = (const float*)d_in[3];
    const float* b_proj = (const float*)d_in[4];
    float* out = (float*)d_out;

    bf16_t* ws = (bf16_t*)d_ws;
    bf16_t* q   = ws;
    bf16_t* k   = ws +     QKV_ELEMS;
    bf16_t* v   = ws + 2 * QKV_ELEMS;
    bf16_t* ao  = ws + 3 * QKV_ELEMS;
    bf16_t* xb  = ao;               // alias: dead once qkv_gemm completes
    bf16_t* wqb = (bf16_t*)d_out;   // alias: out written only by proj at the end

    // Preferred layout: wpb in its own region after ao -> w_proj converted in
    // the SAME first conv launch (one fewer dispatch, no attn->conv->proj
    // serialization stage). Requires ws_size to cover it; else fall back to
    // the R8 aliased layout (wpb over dead k, converted after attn).
    const size_t need = (3 * QKV_ELEMS + AO_ELEMS + WPB_ELEMS) * sizeof(bf16_t);
    if (ws_size >= need) {
        bf16_t* wpb = ws + 3 * QKV_ELEMS + AO_ELEMS;
        conv_bf16_3<<<dim3(4224), 256, 0, stream>>>(
            x, xb, 786432, w_qkv, wqb, 221184, w_proj, wpb, 73728);
        qkv_gemm<<<dim3(64 * 18), 256, 0, stream>>>(xb, wqb, b_qkv, q, k, v);
        attn_fwd<<<dim3(32 * 48), 256, 0, stream>>>(q, k, v, ao);
        proj_gemm<<<dim3(64 * 6), 256, 0, stream>>>(ao, wpb, b_proj, out);
    } else {
        bf16_t* wpb = k;            // alias: k dead after attn
        conv_bf16_3<<<dim3(3936), 256, 0, stream>>>(
            x, xb, 786432, w_qkv, wqb, 221184, (const float*)nullptr, (bf16_t*)nullptr, 0);
        qkv_gemm<<<dim3(64 * 18), 256, 0, stream>>>(xb, wqb, b_qkv, q, k, v);
        attn_fwd<<<dim3(32 * 48), 256, 0, stream>>>(q, k, v, ao);
        conv_bf16_3<<<dim3(288), 256, 0, stream>>>(
            w_proj, wpb, 73728, (const float*)nullptr, (bf16_t*)nullptr, 0,
            (const float*)nullptr, (bf16_t*)nullptr, 0);
        proj_gemm<<<dim3(64 * 6), 256, 0, stream>>>(ao, wpb, b_proj, out);
    }
}